// Round 13
// baseline (56.014 us; speedup 1.0000x reference)
//
#include <hip/hip_runtime.h>
#include <hip/hip_bf16.h>
#include <math.h>

#define NB 16384
#define ND 128
#define NH 512
#define NO 128
#define NE 8
#define EPSF 2.2204460492503131e-16f

using bf16x8 = __attribute__((ext_vector_type(8))) short;
using f32x16 = __attribute__((ext_vector_type(16))) float;
using uint2v = __attribute__((ext_vector_type(2))) unsigned;

// ---- workspace layout (bytes) ----
#define WS_BLKCNT 0u                       // int  [256][8]
#define WS_BLKIMP 8192u                    // float[256][8]
#define WS_TOKID  16384u                   // int  [NE][256*128] (tok | which<<30)
#define WS_TOKGG  1064960u                 // float2[NB]
#define WS_XBF    1196032u                 // ushort[NB][ND]
#define WS_W1F    5390336u                 // ushort frag-linear w1 (1MB)
#define WS_W2F    6438912u                 // ushort frag-linear w2 (1MB)
#define WS_YSTAGE 7487488u                 // ushort[NB][2][NO] gate-prescaled bf16 (8.4MB)

__device__ __forceinline__ unsigned f2bf(float f){
  unsigned u = __float_as_uint(f);
  u += 0x7FFFu + ((u >> 16) & 1u);
  return u >> 16;
}
__device__ __forceinline__ unsigned cvtpk(float lo, float hi){
  unsigned r;
  asm("v_cvt_pk_bf16_f32 %0, %1, %2" : "=v"(r) : "v"(lo), "v"(hi));
  return r;
}
__device__ __forceinline__ void gld16(const void* g, void* l){
  __builtin_amdgcn_global_load_lds((const __attribute__((address_space(1))) void*)g,
                                   (__attribute__((address_space(3))) void*)l, 16, 0, 0);
}

// ============ prep: gating (0-255) + w1 pack (256-511) + w2 pack (512-767) — R11 verbatim
__global__ __launch_bounds__(256) void prep_kernel(
    const float* __restrict__ x, const float* __restrict__ wg,
    const float* __restrict__ w1, const float* __restrict__ w2,
    unsigned short* __restrict__ xbf, unsigned short* __restrict__ w1f,
    unsigned short* __restrict__ w2f, int* __restrict__ blk_cnt,
    float* __restrict__ blk_imp, int* __restrict__ tok_ids, float2* __restrict__ tok_gg){
  int bx = blockIdx.x, tid = threadIdx.x;
  if (bx >= 512){
    int u = (bx - 512)*256 + tid;
    int o = u & 127, hb = (u>>7)&3, c = (u>>9)&15, e = u>>13;
    int h0 = c*32 + (hb>>1)*16 + (hb&1)*8;
    const float* src = w2 + (size_t)e*NH*NO + (size_t)h0*NO + o;
    unsigned q[4];
    #pragma unroll
    for (int p = 0; p < 4; ++p)
      q[p] = f2bf(src[(2*p)*NO]) | (f2bf(src[(2*p+1)*NO]) << 16);
    *(uint4*)(w2f + (size_t)u*8) = make_uint4(q[0], q[1], q[2], q[3]);
    return;
  }
  if (bx >= 256){
    int u = (bx - 256)*256 + tid;
    int h32 = u & 31, db = (u>>5)&15, c = (u>>9)&15, e = u>>13;
    int d0 = (db>>1)*16 + (db&1)*8;
    int hg = c*32 + h32;
    const float* src = w1 + (size_t)e*ND*NH + (size_t)d0*NH + hg;
    unsigned q[4];
    #pragma unroll
    for (int p = 0; p < 4; ++p)
      q[p] = f2bf(src[(2*p)*NH]) | (f2bf(src[(2*p+1)*NH]) << 16);
    *(uint4*)(w1f + (size_t)u*8) = make_uint4(q[0], q[1], q[2], q[3]);
    return;
  }
  __shared__ int   lcnt[NE];
  __shared__ float limp[NE];
  if (tid < NE){ lcnt[tid] = 0; limp[tid] = 0.f; }
  __syncthreads();
  int tok  = bx*64 + (tid >> 2);
  int part = tid & 3;
  const float4* xr4 = (const float4*)(x + (size_t)tok*ND);
  double acc[NE];
  #pragma unroll
  for (int e = 0; e < NE; ++e) acc[e] = 0.0;
  #pragma unroll
  for (int j = 0; j < 8; ++j){
    int f4 = part + j*4;
    float4 v = xr4[f4];
    uint2 p;
    p.x = f2bf(v.x) | (f2bf(v.y) << 16);
    p.y = f2bf(v.z) | (f2bf(v.w) << 16);
    *(uint2*)(xbf + (size_t)tok*ND + f4*4) = p;
    const float4* wr = (const float4*)(wg + f4*32);
    float vm[4] = {v.x, v.y, v.z, v.w};
    #pragma unroll
    for (int m = 0; m < 4; ++m){
      float4 wa = wr[2*m], wb = wr[2*m+1];
      double d = (double)vm[m];
      acc[0] += d*(double)wa.x; acc[1] += d*(double)wa.y;
      acc[2] += d*(double)wa.z; acc[3] += d*(double)wa.w;
      acc[4] += d*(double)wb.x; acc[5] += d*(double)wb.y;
      acc[6] += d*(double)wb.z; acc[7] += d*(double)wb.w;
    }
  }
  #pragma unroll
  for (int e = 0; e < NE; ++e){
    acc[e] += __shfl_xor(acc[e], 1);
    acc[e] += __shfl_xor(acc[e], 2);
  }
  if (part == 0){
    int i0 = 0;
    double l0 = acc[0];
    #pragma unroll
    for (int e = 1; e < NE; ++e) if (acc[e] > l0){ l0 = acc[e]; i0 = e; }
    int i1 = (i0 == 0) ? 1 : 0;
    double l1 = acc[i1];
    #pragma unroll
    for (int e = 0; e < NE; ++e) if (e != i0 && acc[e] > l1){ l1 = acc[e]; i1 = e; }
    float e1 = expf((float)(l1 - l0));
    float g0 = 1.0f/(1.0f + e1);
    float g1 = e1/(1.0f + e1);
    int s0 = atomicAdd(&lcnt[i0], 1);
    int s1 = atomicAdd(&lcnt[i1], 1);
    atomicAdd(&limp[i0], g0);
    atomicAdd(&limp[i1], g1);
    tok_gg[tok] = make_float2(g0, g1);
    tok_ids[i0*32768 + bx*128 + s0] = tok;
    tok_ids[i1*32768 + bx*128 + s1] = tok | (1 << 30);
  }
  __syncthreads();
  if (tid < NE){
    blk_cnt[bx*8 + tid] = lcnt[tid];
    blk_imp[bx*8 + tid] = limp[tid];
  }
}

// ============ experts: SINGLE-WAVE blocks (64 thr), 64-token tiles, ~520 blocks.
// Zero barriers (wave-synchronous). 16 chunks of 32h, 2-deep gld16 prefetch with
// counted s_waitcnt vmcnt(16) (T4). Each wave = 2 token-Mfrags -> every w1/w2
// ds_read feeds 2 MFMAs. Bias pre-staged in LDS so in-loop VMEM = staging only.
__global__ __launch_bounds__(64, 1) void expert_kernel(
    const unsigned short* __restrict__ xbf, const unsigned short* __restrict__ w1f,
    const unsigned short* __restrict__ w2f, const float* __restrict__ b1,
    const float* __restrict__ b2, const int* __restrict__ blk_cnt,
    const int* __restrict__ tok_ids, const float2* __restrict__ tok_gg,
    unsigned short* __restrict__ ystage){
  __shared__ char L[35200];
  char*  wbuf   = L;                      // [2][16384] : [bsel]{w1 8K | w2 8K}
  int*   cnt_l  = (int*)L;                // [8][256]  (overlaps wbuf, prologue-only)
  int*   gp     = (int*)(L + 8192);       // [8][32]   (overlaps wbuf, prologue-only)
  int*   sl_tok = (int*)(L + 32768);      // [64]
  float* b1s    = (float*)(L + 33024);    // [512]
  int*   totl   = (int*)(L + 35072);      // [8]
  int*   tbase  = (int*)(L + 35104);      // [9]
  int lane = threadIdx.x, l31 = lane & 31, hi = lane >> 5;

  // ---- prologue (wave-synchronous, no barriers) ----
  #pragma unroll
  for (int j = 0; j < 4; ++j){            // transpose count matrix
    int blk = lane + j*64;
    int4 a = *(const int4*)(blk_cnt + blk*8);
    int4 c4 = *(const int4*)(blk_cnt + blk*8 + 4);
    cnt_l[0*256+blk]=a.x;  cnt_l[1*256+blk]=a.y;  cnt_l[2*256+blk]=a.z;  cnt_l[3*256+blk]=a.w;
    cnt_l[4*256+blk]=c4.x; cnt_l[5*256+blk]=c4.y; cnt_l[6*256+blk]=c4.z; cnt_l[7*256+blk]=c4.w;
  }
  asm volatile("s_waitcnt lgkmcnt(0)" ::: "memory");
  #pragma unroll
  for (int p = 0; p < 4; ++p){            // per-expert group-8 sums + 32-wide scan
    int e8 = p*2 + hi, g = l31;
    int s8 = 0;
    #pragma unroll
    for (int i = 0; i < 8; ++i) s8 += cnt_l[e8*256 + g*8 + i];
    int pre = s8;
    #pragma unroll
    for (int st = 1; st < 32; st <<= 1){
      int o = __shfl_up(pre, st, 32);
      if (g >= st) pre += o;
    }
    gp[e8*32 + g] = pre;
    if (g == 31) totl[e8] = pre;
  }
  asm volatile("s_waitcnt lgkmcnt(0)" ::: "memory");
  if (lane == 0){
    tbase[0] = 0;
    #pragma unroll
    for (int e = 0; e < NE; ++e) tbase[e+1] = tbase[e] + ((totl[e] + 63) >> 6);
  }
  asm volatile("s_waitcnt lgkmcnt(0)" ::: "memory");
  int b = blockIdx.x;
  if (b >= tbase[8]) return;
  int e = 0;
  #pragma unroll
  for (int ee = 1; ee < NE; ++ee) if (tbase[ee] <= b) e = ee;
  int n_e  = totl[e];
  int base = (b - tbase[e])*64;
  {                                       // resolve this tile's 64 slots -> tokens
    int s = base + lane;
    if (s >= n_e) s = n_e - 1;
    int g = 0;
    #pragma unroll
    for (int st = 16; st; st >>= 1){
      int c = g + st;
      if (c <= 31 && gp[e*32 + c - 1] <= s) g = c;
    }
    int acc2 = g ? gp[e*32 + g - 1] : 0;
    int gb = g*8;
    while (true){
      int c2 = cnt_l[e*256 + gb];
      if (acc2 + c2 > s) break;
      acc2 += c2; ++gb;
    }
    sl_tok[lane] = tok_ids[e*32768 + gb*128 + (s - acc2)];
  }
  asm volatile("s_waitcnt lgkmcnt(0)" ::: "memory");
  // stage bias (2 gld16) — after this, loop VMEM = counted staging only
  gld16((const char*)(b1 + e*NH) + lane*16, b1s);
  gld16((const char*)(b1 + e*NH) + 1024 + lane*16, (char*)b1s + 1024);
  // x fragments for both token groups
  int tokA = sl_tok[l31] & 0x3FFFFFFF;
  int tokB = sl_tok[32 + l31] & 0x3FFFFFFF;
  bf16x8 xfA[8], xfB[8];
  #pragma unroll
  for (int k = 0; k < 8; ++k){
    xfA[k] = *(const bf16x8*)(xbf + (size_t)tokA*ND + (k*2 + hi)*8);
    xfB[k] = *(const bf16x8*)(xbf + (size_t)tokB*ND + (k*2 + hi)*8);
  }
  const char* g1base = (const char*)w1f + (size_t)e*131072;
  const char* g2base = (const char*)w2f + (size_t)e*131072;

#define STAGE(c, bsel) do { \
    const char* _g1 = g1base + (size_t)(c)*8192 + lane*16; \
    const char* _g2 = g2base + (size_t)(c)*8192 + lane*16; \
    char* _l1 = wbuf + (bsel)*16384; \
    char* _l2 = wbuf + (bsel)*16384 + 8192; \
    _Pragma("unroll") \
    for (int _i = 0; _i < 8; ++_i){ \
      gld16(_g1 + _i*1024, _l1 + _i*1024); \
      gld16(_g2 + _i*1024, _l2 + _i*1024); \
    } \
  } while(0)

#define REPACK(dv, out0, out1) do { \
    unsigned A0=cvtpk(dv[0],dv[1]),   A1=cvtpk(dv[2],dv[3]); \
    unsigned A2=cvtpk(dv[4],dv[5]),   A3=cvtpk(dv[6],dv[7]); \
    unsigned A4=cvtpk(dv[8],dv[9]),   A5=cvtpk(dv[10],dv[11]); \
    unsigned A6=cvtpk(dv[12],dv[13]), A7=cvtpk(dv[14],dv[15]); \
    uint2v r0 = __builtin_amdgcn_permlane32_swap(A0, A2, false, false); \
    uint2v r1 = __builtin_amdgcn_permlane32_swap(A1, A3, false, false); \
    uint2v r2 = __builtin_amdgcn_permlane32_swap(A4, A6, false, false); \
    uint2v r3 = __builtin_amdgcn_permlane32_swap(A5, A7, false, false); \
    union { unsigned u[4]; bf16x8 v; } fa, fb; \
    fa.u[0]=r0[0]; fa.u[1]=r1[0]; fa.u[2]=r0[1]; fa.u[3]=r1[1]; \
    fb.u[0]=r2[0]; fb.u[1]=r3[0]; fb.u[2]=r2[1]; fb.u[3]=r3[1]; \
    out0 = fa.v; out1 = fb.v; \
  } while(0)

  STAGE(0, 0);
  STAGE(1, 1);
  f32x16 yA[4], yB[4];
  #pragma unroll
  for (int ot = 0; ot < 4; ++ot)
    #pragma unroll
    for (int i = 0; i < 16; ++i){ yA[ot][i] = 0.f; yB[ot][i] = 0.f; }

  #pragma unroll
  for (int c = 0; c < 16; ++c){
    if (c < 14) asm volatile("s_waitcnt vmcnt(16)" ::: "memory");
    else        asm volatile("s_waitcnt vmcnt(0)"  ::: "memory");
    __builtin_amdgcn_sched_barrier(0);
    const char* w1c = wbuf + (c & 1)*16384;
    const char* w2c = wbuf + (c & 1)*16384 + 8192;
    // stage 1: h^T for both token groups (each a-frag feeds 2 MFMAs)
    f32x16 hA, hB;
    #pragma unroll
    for (int i = 0; i < 16; ++i){ hA[i] = 0.f; hB[i] = 0.f; }
    #pragma unroll
    for (int k = 0; k < 8; ++k){
      bf16x8 a = *(const bf16x8*)(w1c + (k*2 + hi)*512 + l31*16);
      hA = __builtin_amdgcn_mfma_f32_32x32x16_bf16(a, xfA[k], hA, 0, 0, 0);
      hB = __builtin_amdgcn_mfma_f32_32x32x16_bf16(a, xfB[k], hB, 0, 0, 0);
    }
    // bias + relu from LDS-staged b1
    float dvA[16], dvB[16];
    #pragma unroll
    for (int g = 0; g < 4; ++g){
      float4 bv = *(const float4*)(b1s + c*32 + hi*4 + g*8);
      dvA[4*g+0] = fmaxf(hA[4*g+0] + bv.x, 0.f);
      dvA[4*g+1] = fmaxf(hA[4*g+1] + bv.y, 0.f);
      dvA[4*g+2] = fmaxf(hA[4*g+2] + bv.z, 0.f);
      dvA[4*g+3] = fmaxf(hA[4*g+3] + bv.w, 0.f);
      dvB[4*g+0] = fmaxf(hB[4*g+0] + bv.x, 0.f);
      dvB[4*g+1] = fmaxf(hB[4*g+1] + bv.y, 0.f);
      dvB[4*g+2] = fmaxf(hB[4*g+2] + bv.z, 0.f);
      dvB[4*g+3] = fmaxf(hB[4*g+3] + bv.w, 0.f);
    }
    bf16x8 ahA0, ahA1, ahB0, ahB1;
    REPACK(dvA, ahA0, ahA1);
    REPACK(dvB, ahB0, ahB1);
    // stage 2: each b-frag feeds 2 MFMAs (both token groups)
    #pragma unroll
    for (int ot = 0; ot < 4; ++ot){
      bf16x8 bf0 = *(const bf16x8*)(w2c + hi*2048 + (ot*32 + l31)*16);
      bf16x8 bf1 = *(const bf16x8*)(w2c + (2 + hi)*2048 + (ot*32 + l31)*16);
      yA[ot] = __builtin_amdgcn_mfma_f32_32x32x16_bf16(ahA0, bf0, yA[ot], 0, 0, 0);
      yA[ot] = __builtin_amdgcn_mfma_f32_32x32x16_bf16(ahA1, bf1, yA[ot], 0, 0, 0);
      yB[ot] = __builtin_amdgcn_mfma_f32_32x32x16_bf16(ahB0, bf0, yB[ot], 0, 0, 0);
      yB[ot] = __builtin_amdgcn_mfma_f32_32x32x16_bf16(ahB1, bf1, yB[ot], 0, 0, 0);
    }
    if (c + 2 < 16){
      asm volatile("s_waitcnt lgkmcnt(0)" ::: "memory");   // ds reads done before overwrite
      __builtin_amdgcn_sched_barrier(0);
      STAGE(c + 2, c & 1);
    }
  }
#undef STAGE
#undef REPACK

  // ---- epilogue: gate-scaled bf16 ystage writes for both groups ----
  float b2v[4];
  #pragma unroll
  for (int ot = 0; ot < 4; ++ot) b2v[ot] = b2[e*NO + ot*32 + l31];
#define EPI(G, Y) do { \
    _Pragma("unroll") \
    for (int r = 0; r < 16; ++r){ \
      int row = (r & 3) + 8*(r >> 2) + 4*hi; \
      int slot = base + (G)*32 + row; \
      if (slot < n_e){ \
        int rw = sl_tok[(G)*32 + row]; \
        int tk = rw & 0x3FFFFFFF, wh = (rw >> 30) & 1; \
        float2 gg = tok_gg[tk]; \
        float gsc = wh ? gg.y : gg.x; \
        unsigned short* dst = ystage + ((size_t)tk*2 + wh)*NO + l31; \
        _Pragma("unroll") \
        for (int ot = 0; ot < 4; ++ot) \
          dst[ot*32] = (unsigned short)f2bf((Y[ot][r] + b2v[ot]) * gsc); \
      } \
    } \
  } while(0)
  EPI(0, yA);
  EPI(1, yB);
#undef EPI
}

// ============ combine — R11 verbatim (y = row0+row1, eps-fix; loss in block 0)
__global__ __launch_bounds__(256) void combine_kernel(
    const unsigned short* __restrict__ ystage, const int* __restrict__ blk_cnt,
    const float* __restrict__ blk_imp, float* __restrict__ y){
  if (blockIdx.x == 0){
    __shared__ int   scnt[32];
    __shared__ float simp[32];
    int tid = threadIdx.x, lane = tid & 63, wid = tid >> 6;
    int4 ca = *(const int4*)(blk_cnt + tid*8);
    int4 cb = *(const int4*)(blk_cnt + tid*8 + 4);
    float4 ia = *(const float4*)(blk_imp + tid*8);
    float4 ib = *(const float4*)(blk_imp + tid*8 + 4);
    int   cv[8] = {ca.x, ca.y, ca.z, ca.w, cb.x, cb.y, cb.z, cb.w};
    float iv[8] = {ia.x, ia.y, ia.z, ia.w, ib.x, ib.y, ib.z, ib.w};
    #pragma unroll
    for (int e = 0; e < NE; ++e){
      int   rc = cv[e];
      float ri = iv[e];
      #pragma unroll
      for (int st = 1; st < 64; st <<= 1){
        rc += __shfl_xor(rc, st);
        ri += __shfl_xor(ri, st);
      }
      if (lane == 0){ scnt[e*4 + wid] = rc; simp[e*4 + wid] = ri; }
    }
    __syncthreads();
    if (tid == 0){
      double si = 0, sqi = 0, sl = 0, sql = 0;
      #pragma unroll
      for (int e = 0; e < NE; ++e){
        double a = (double)(simp[e*4] + simp[e*4+1] + simp[e*4+2] + simp[e*4+3]);
        double bb = (double)(scnt[e*4] + scnt[e*4+1] + scnt[e*4+2] + scnt[e*4+3]);
        si += a; sqi += a*a; sl += bb; sql += bb*bb;
      }
      double mi = si/8.0, vi = (sqi - 8.0*mi*mi)/7.0;
      double ml = sl/8.0, vl = (sql - 8.0*ml*ml)/7.0;
      y[NB*NO] = (float)(vi/(mi*mi + 1e-10) + vl/(ml*ml + 1e-10));
    }
  }
  int idx = blockIdx.x*256 + threadIdx.x;
  int tk = idx >> 4, q = idx & 15;
  const unsigned short* r0 = ystage + (size_t)tk*256 + q*8;
  uint4 a = *(const uint4*)r0;
  uint4 bq = *(const uint4*)(r0 + 128);
  unsigned aw[4] = {a.x, a.y, a.z, a.w};
  unsigned bw[4] = {bq.x, bq.y, bq.z, bq.w};
  float outs[8];
  #pragma unroll
  for (int i = 0; i < 4; ++i){
    float vlo = __uint_as_float(aw[i] << 16)         + __uint_as_float(bw[i] << 16);
    float vhi = __uint_as_float(aw[i] & 0xFFFF0000u) + __uint_as_float(bw[i] & 0xFFFF0000u);
    outs[2*i]   = (vlo == 0.f) ? EPSF : vlo;
    outs[2*i+1] = (vhi == 0.f) ? EPSF : vhi;
  }
  float4 o0 = {outs[0], outs[1], outs[2], outs[3]};
  float4 o1 = {outs[4], outs[5], outs[6], outs[7]};
  float* dst = y + (size_t)tk*128 + q*8;
  *(float4*)dst     = o0;
  *(float4*)(dst+4) = o1;
}

extern "C" void kernel_launch(void* const* d_in, const int* in_sizes, int n_in,
                              void* d_out, int out_size, void* d_ws, size_t ws_size,
                              hipStream_t stream){
  (void)in_sizes; (void)n_in; (void)out_size; (void)ws_size;
  const float* x  = (const float*)d_in[0];
  const float* wg = (const float*)d_in[1];
  const float* w1 = (const float*)d_in[2];
  const float* b1 = (const float*)d_in[3];
  const float* w2 = (const float*)d_in[4];
  const float* b2 = (const float*)d_in[5];
  float* out = (float*)d_out;
  char* ws = (char*)d_ws;
  int*            blk_cnt = (int*)(ws + WS_BLKCNT);
  float*          blk_imp = (float*)(ws + WS_BLKIMP);
  int*            tok_ids = (int*)(ws + WS_TOKID);
  float2*         tok_gg  = (float2*)(ws + WS_TOKGG);
  unsigned short* xbf     = (unsigned short*)(ws + WS_XBF);
  unsigned short* w1f     = (unsigned short*)(ws + WS_W1F);
  unsigned short* w2f     = (unsigned short*)(ws + WS_W2F);
  unsigned short* ystage  = (unsigned short*)(ws + WS_YSTAGE);

  prep_kernel<<<768, 256, 0, stream>>>(x, wg, w1, w2, xbf, w1f, w2f,
                                       blk_cnt, blk_imp, tok_ids, tok_gg);
  expert_kernel<<<520, 64, 0, stream>>>(xbf, w1f, w2f, b1, b2,
                                        blk_cnt, tok_ids, tok_gg, ystage);
  combine_kernel<<<1024, 256, 0, stream>>>(ystage, blk_cnt, blk_imp, out);
}